// Round 12
// baseline (6803.370 us; speedup 1.0000x reference)
//
#include <hip/hip_runtime.h>
#include <math.h>

#define LL 6
#define HH 6
#define EE 384
#define FF 1536
#define TT 256
#define BB 256
#define VV 65
constexpr int BT = BB * TT;                 // 65536 rows total

typedef __attribute__((ext_vector_type(8))) short s16x8;   // 8 bf16 (4 VGPR)
typedef __attribute__((ext_vector_type(4))) float f32x4;
typedef __attribute__((ext_vector_type(2))) unsigned int u32x2;
typedef unsigned int uint;
typedef unsigned short ushort_t;

__device__ __forceinline__ float uaf(uint u) { union { uint u; float f; } c; c.u = u; return c.f; }
__device__ __forceinline__ ushort_t f2b(float f) {
  union { float f; uint u; } c; c.f = f;
  uint r = c.u + 0x7fffu + ((c.u >> 16) & 1u);          // RNE
  return (ushort_t)(r >> 16);
}
__device__ __forceinline__ float b2f(ushort_t b) { return uaf((uint)b << 16); }
__device__ __forceinline__ float blo(uint u) { return uaf(u << 16); }
__device__ __forceinline__ float bhi(uint u) { return uaf(u & 0xffff0000u); }
__device__ __forceinline__ uint pack2(float a, float b) {
  return (uint)f2b(a) | ((uint)f2b(b) << 16);
}

__device__ __forceinline__ void gload_lds16(const void* g, void* l) {
  __builtin_amdgcn_global_load_lds(
      (const __attribute__((address_space(1))) unsigned int*)g,
      (__attribute__((address_space(3))) unsigned int*)l, 16, 0, 0);
}

// ------- embed + layer-0 LN fused: x = bf16(tok+pos); hb = LN(x) -------
__global__ __launch_bounds__(256)
void embed_ln(const int* __restrict__ inp, const float* __restrict__ tok,
              const float* __restrict__ pos, const float* __restrict__ g,
              const float* __restrict__ b, ushort_t* __restrict__ x,
              ushort_t* __restrict__ outp) {
  int wid = threadIdx.x >> 6, lane = threadIdx.x & 63;
  int row = blockIdx.x * 4 + wid;
  int t = row % TT;
  int tk = inp[row];
  const float* tr = tok + (size_t)tk * EE;
  const float* pr = pos + (size_t)t * EE;
  float v[6];
  float s = 0.f, s2 = 0.f;
#pragma unroll
  for (int i = 0; i < 3; ++i) {
    int e = 2 * lane + 128 * i;
    float2 a = *(const float2*)&tr[e];
    float2 p2 = *(const float2*)&pr[e];
    v[2 * i] = a.x + p2.x;
    v[2 * i + 1] = a.y + p2.y;
    s += v[2 * i] + v[2 * i + 1];
    s2 += v[2 * i] * v[2 * i] + v[2 * i + 1] * v[2 * i + 1];
  }
#pragma unroll
  for (int off = 32; off; off >>= 1) {
    s += __shfl_xor(s, off);
    s2 += __shfl_xor(s2, off);
  }
  float mu = s * (1.f / EE);
  float var = s2 * (1.f / EE) - mu * mu;
  float rs = rsqrtf(var + 1e-5f);
  uint* x32 = (uint*)x;
  uint* o32 = (uint*)outp;
#pragma unroll
  for (int i = 0; i < 3; ++i) {
    int e = 2 * lane + 128 * i;
    float2 gg = *(const float2*)&g[e];
    float2 bb = *(const float2*)&b[e];
    int slot = row * 192 + lane + 64 * i;
    x32[slot] = pack2(v[2 * i], v[2 * i + 1]);
    o32[slot] = pack2((v[2 * i] - mu) * rs * gg.x + bb.x,
                      (v[2 * i + 1] - mu) * rs * gg.y + bb.y);
  }
}

// ------- pack QKV weights: [l][h][e][d] f32 -> bf16 [l][n=1152][k=384] -------
__global__ __launch_bounds__(256)
void pack_qkv(const float* __restrict__ Wq, const float* __restrict__ Wk,
              const float* __restrict__ Wv, ushort_t* __restrict__ dst) {
  int idx = blockIdx.x * 256 + threadIdx.x;
  int l = idx / (1152 * 384);
  int r = idx % (1152 * 384);
  int n = r / 384;
  int k = r % 384;
  int which = n / 384;                            // 0:q 1:k 2:v
  int hd = n % 384;
  int h = hd >> 6, d = hd & 63;
  const float* src = which == 0 ? Wq : (which == 1 ? Wk : Wv);
  dst[idx] = f2b(src[((size_t)(l * HH + h) * EE + k) * 64 + d]);
}

// ------- pack generic weight: [l][k][n] f32 -> bf16 [l][n][k] -------
__global__ __launch_bounds__(256)
void pack_wt(const float* __restrict__ src, ushort_t* __restrict__ dst, int Kd, int Nd) {
  int idx = blockIdx.x * 256 + threadIdx.x;
  int l = idx / (Kd * Nd);
  int r = idx % (Kd * Nd);
  int n = r / Kd;
  int k = r % Kd;
  dst[idx] = f2b(src[((size_t)l * Kd + k) * Nd + n]);
}

// ------- pack head: Wh [384][65] f32 -> bf16 [128][384], zero-pad -------
__global__ __launch_bounds__(256)
void pack_head(const float* __restrict__ Wh, ushort_t* __restrict__ dst) {
  int idx = blockIdx.x * 256 + threadIdx.x;
  int n = idx / 384, k = idx % 384;
  dst[idx] = (n < VV) ? f2b(Wh[(size_t)k * VV + n]) : (ushort_t)0;
}

// ------------- bf16 MFMA GEMM, double-buffered, counted-vmcnt pipeline -------------
// A[M,K] bf16, Wt[N,K] bf16 (W^T). M%128==0, N%128==0, K%32==0.
// MODE 0: Cb[M,N] bf16 = (relu)(acc+bias)   [LDS-coalesced writes]
// MODE 2: head — Cf f32, stride VV, cols<VV
// MODE 3: qkv split — cols<768 -> Cb stride 768 (coalesced); cols>=768 -> Cv[col-768][M]
template <int MODE, bool BIAS, bool RELU>
__global__ __launch_bounds__(256)
void gemm_bf16(const ushort_t* __restrict__ A, const ushort_t* __restrict__ Wt,
               const float* __restrict__ bias, ushort_t* __restrict__ Cb,
               float* __restrict__ Cf, ushort_t* __restrict__ Cv,
               int M, int N, int K, int nx) {
  __shared__ ushort_t sm[16896];                  // staging 2x(4096+4096) | ep 128x132
  ushort_t* As = sm;
  ushort_t* Bs = sm + 8192;
  const int tid = threadIdx.x;

  int bid = blockIdx.x;
  {
    const int nwg = gridDim.x;
    const int q = nwg >> 3, rr = nwg & 7;
    const int xcd = bid & 7, within = bid >> 3;
    bid = (xcd < rr ? xcd * (q + 1) : rr * (q + 1) + (xcd - rr) * q) + within;
  }
  const int bn = (bid % nx) * 128;
  const int bm = (bid / nx) * 128;

  const int w = tid >> 6, lane = tid & 63;
  const int wr = (w >> 1) * 64, wc = (w & 1) * 64;
  const int fr = lane & 15, fq = lane >> 4;

  // staging addressing (slot-XOR swizzle, round-3-verified)
  const int rp = lane >> 2;
  const int fqs = (lane & 3) ^ ((rp >> 1) & 3);
  const ushort_t* Ag0 = A + (size_t)(bm + w * 16 + rp) * K + fqs * 8;
  const ushort_t* Ag1 = Ag0 + (size_t)64 * K;
  const ushort_t* Bg0 = Wt + (size_t)(bn + w * 16 + rp) * K + fqs * 8;
  const ushort_t* Bg1 = Bg0 + (size_t)64 * K;

  const int slotr = (fq ^ ((fr >> 1) & 3)) * 8;
  const ushort_t* Ard = As + (wr + fr) * 32 + slotr;
  const ushort_t* Brd = Bs + (wc + fr) * 32 + slotr;

  const int nt = K >> 5;
  auto STAGE = [&](int kt, int b) {
    const int k0 = kt << 5;
    const int bo = b << 12;                       // 4096 elems per buffer
    gload_lds16(Ag0 + k0, As + bo + (w * 16) * 32);
    gload_lds16(Ag1 + k0, As + bo + (64 + w * 16) * 32);
    gload_lds16(Bg0 + k0, Bs + bo + (w * 16) * 32);
    gload_lds16(Bg1 + k0, Bs + bo + (64 + w * 16) * 32);
  };

  f32x4 acc[4][4] = {};
  STAGE(0, 0);

  for (int t = 0; t < nt; ++t) {
    const int bo = (t & 1) << 12;
    if (t + 1 < nt) {
      STAGE(t + 1, (t & 1) ^ 1);                  // next tile's 4 loads in flight
      asm volatile("s_waitcnt vmcnt(4)" ::: "memory");   // wait buf t only
    } else {
      asm volatile("s_waitcnt vmcnt(0)" ::: "memory");
    }
    __builtin_amdgcn_s_barrier();                 // all waves: buf t written
    __builtin_amdgcn_sched_barrier(0);
    s16x8 afr[4], bfr[4];
#pragma unroll
    for (int m = 0; m < 4; ++m) afr[m] = *(const s16x8*)(Ard + bo + m * 512);
#pragma unroll
    for (int n = 0; n < 4; ++n) bfr[n] = *(const s16x8*)(Brd + bo + n * 512);
#pragma unroll
    for (int m = 0; m < 4; ++m)
#pragma unroll
      for (int n = 0; n < 4; ++n)
        acc[m][n] = __builtin_amdgcn_mfma_f32_16x16x32_bf16(afr[m], bfr[n], acc[m][n], 0, 0, 0);
    __builtin_amdgcn_sched_barrier(0);
    __builtin_amdgcn_s_barrier();                 // reads done before buf overwrite
  }

  // epilogue: D row = (lane>>4)*4 + j, col = lane&15
  if constexpr (MODE == 0 || MODE == 3) {
    if (MODE == 3 && bn >= 768) {                 // V region: write V^T [384][M]
      const int r0 = bm + wr + fq * 4;
      const int c0 = bn + wc + fr;
#pragma unroll
      for (int n = 0; n < 4; ++n) {
        const int col = c0 + n * 16 - 768;
#pragma unroll
        for (int m = 0; m < 4; ++m) {
          const int row = r0 + m * 16;
          uint lo = (uint)f2b(acc[m][n][0]) | ((uint)f2b(acc[m][n][1]) << 16);
          uint hi = (uint)f2b(acc[m][n][2]) | ((uint)f2b(acc[m][n][3]) << 16);
          *(u32x2*)&Cv[(size_t)col * M + row] = u32x2{lo, hi};
        }
      }
      return;
    }
    // LDS-bounce coalesced store: tile -> ep[128][132] -> 16B/lane rows
    const int ostride = (MODE == 3) ? 768 : N;
#pragma unroll
    for (int n = 0; n < 4; ++n) {
      const int col = wc + n * 16 + fr;
      const float bv = BIAS ? bias[bn + col] : 0.f;
#pragma unroll
      for (int m = 0; m < 4; ++m) {
        const int row = wr + m * 16 + fq * 4;
#pragma unroll
        for (int j = 0; j < 4; ++j) {
          float vv = acc[m][n][j] + bv;
          if constexpr (RELU) vv = fmaxf(vv, 0.f);
          sm[(row + j) * 132 + col] = f2b(vv);    // fq -> +8 banks: conflict-free
        }
      }
    }
    __syncthreads();
    const int rr2 = tid >> 4, cb = (tid & 15) * 8;
#pragma unroll
    for (int pp = 0; pp < 8; ++pp) {
      const int row = pp * 16 + rr2;
      s16x8 v8 = *(const s16x8*)(sm + row * 132 + cb);
      *(s16x8*)(Cb + (size_t)(bm + row) * ostride + bn + cb) = v8;
    }
    return;
  }
  // MODE 2: head, f32 logits stride VV, cols < VV
  const int r0 = bm + wr + fq * 4;
  const int c0 = bn + wc + fr;
#pragma unroll
  for (int n = 0; n < 4; ++n) {
    const int col = c0 + n * 16;
    if (col >= VV) continue;
    const float bv = BIAS ? bias[col] : 0.f;
#pragma unroll
    for (int m = 0; m < 4; ++m) {
      const int row = r0 + m * 16;
#pragma unroll
      for (int j = 0; j < 4; ++j)
        Cf[(size_t)(row + j) * VV + col] = acc[m][n][j] + bv;
    }
  }
}

// ------- fused GEMM(N=384) + residual + LayerNorm (coalesced epilogue v2) -------
// delta = A@Wt^T + bias; v = x + delta; x <- v; out <- LN(v; g, b).
// 512 threads, BM=128, BN=384. 8 waves = 2M x 4N, wave tile 64x96.
__global__ __launch_bounds__(512, 4)
void gemm_resln(const ushort_t* __restrict__ A, const ushort_t* __restrict__ Wt,
                const float* __restrict__ bias, ushort_t* __restrict__ x,
                const float* __restrict__ g, const float* __restrict__ b,
                ushort_t* __restrict__ outp, int M, int K) {
  __shared__ ushort_t sm[32768];                  // A 2x4096 | B 2x12288 (64 KB)
  ushort_t* As = sm;
  ushort_t* Bs = sm + 8192;
  const int tid = threadIdx.x;

  int bid = blockIdx.x;
  {
    const int nwg = gridDim.x;
    const int q = nwg >> 3, rm = nwg & 7;
    const int xcd = bid & 7, within = bid >> 3;
    bid = (xcd < rm ? xcd * (q + 1) : rm * (q + 1) + (xcd - rm) * q) + within;
  }
  const int bm = bid * 128;

  const int w = tid >> 6, lane = tid & 63;
  const int wm = w >> 2, wn = w & 3;
  const int wr = wm * 64, wc = wn * 96;
  const int fr = lane & 15, fq = lane >> 4;

  const int rp = lane >> 2;
  const int fqs = (lane & 3) ^ ((rp >> 1) & 3);
  const ushort_t* Ag = A + (size_t)(bm + w * 16 + rp) * K + fqs * 8;
  const ushort_t* Bg = Wt + (size_t)(w * 16 + rp) * K + fqs * 8;

  const int slotr = (fq ^ ((fr >> 1) & 3)) * 8;
  const ushort_t* Ard = As + (wr + fr) * 32 + slotr;
  const ushort_t* Brd = Bs + (wc + fr) * 32 + slotr;

  const int nt = K >> 5;
  auto STAGE = [&](int kt, int bsel) {
    const int k0 = kt << 5;
    gload_lds16(Ag + k0, As + (bsel ? 4096 : 0) + (w * 16) * 32);
    const int bo = bsel ? 12288 : 0;
#pragma unroll
    for (int gi = 0; gi < 3; ++gi)
      gload_lds16(Bg + (size_t)(128 * gi) * K + k0,
                  Bs + bo + (gi * 128 + w * 16) * 32);
  };

  f32x4 acc[4][6] = {};
  STAGE(0, 0);

  for (int t = 0; t < nt; ++t) {
    const int aob = (t & 1) ? 4096 : 0;
    const int bob = (t & 1) ? 12288 : 0;
    if (t + 1 < nt) {
      STAGE(t + 1, (t & 1) ^ 1);                  // 4 loads/thread in flight
      asm volatile("s_waitcnt vmcnt(4)" ::: "memory");
    } else {
      asm volatile("s_waitcnt vmcnt(0)" ::: "memory");
    }
    __builtin_amdgcn_s_barrier();
    __builtin_amdgcn_sched_barrier(0);
    s16x8 afr[4], bfr[6];
#pragma unroll
    for (int m = 0; m < 4; ++m) afr[m] = *(const s16x8*)(Ard + aob + m * 512);
#pragma unroll
    for (int n = 0; n < 6; ++n) bfr[n] = *(const s16x8*)(Brd + bob + n * 512);
#pragma unroll
    for (int m = 0; m < 4; ++m)
#pragma unroll
      for (int n = 0; n < 6; ++n)
        acc[m][n] = __builtin_amdgcn_mfma_f32_16x16x32_bf16(afr[m], bfr[n], acc[m][n], 0, 0, 0);
    __builtin_amdgcn_sched_barrier(0);
    __builtin_amdgcn_s_barrier();
  }

  // epilogue: two 64-row halves through LDS tile [64][388] bf16.
  // LN phase uses ln_res-verified coalesced indexing: uint slot = row*192 + 64*i + lane.
  uint* x32 = (uint*)x;
  uint* o32 = (uint*)outp;
  const uint* smu = (const uint*)sm;
#pragma unroll
  for (int h = 0; h < 2; ++h) {
    if (wm == h) {                                // this half's owner waves write delta
#pragma unroll
      for (int n = 0; n < 6; ++n) {
        const int col = wc + n * 16 + fr;
        const float bv = bias[col];
#pragma unroll
        for (int m = 0; m < 4; ++m) {
          const int rr = m * 16 + fq * 4;
#pragma unroll
          for (int j = 0; j < 4; ++j)
            sm[(rr + j) * 388 + col] = f2b(acc[m][n][j] + bv);
        }
      }
    }
    __syncthreads();
    // each wave finishes 8 rows (delta from LDS, x from global; all coalesced)
#pragma unroll
    for (int rr = 0; rr < 8; ++rr) {
      const int rih = w * 8 + rr;
      const int row = h * 64 + rih;
      const size_t xbase = (size_t)(bm + row) * 192;
      float v[6];
      float s = 0.f, s2 = 0.f;
#pragma unroll
      for (int i = 0; i < 3; ++i) {
        uint du = smu[rih * 194 + 64 * i + lane];
        uint xu = x32[xbase + 64 * i + lane];
        v[2 * i] = blo(du) + blo(xu);
        v[2 * i + 1] = bhi(du) + bhi(xu);
        s += v[2 * i] + v[2 * i + 1];
        s2 += v[2 * i] * v[2 * i] + v[2 * i + 1] * v[2 * i + 1];
      }
#pragma unroll
      for (int off = 32; off; off >>= 1) {
        s += __shfl_xor(s, off);
        s2 += __shfl_xor(s2, off);
      }
      float mu = s * (1.f / EE);
      float var = s2 * (1.f / EE) - mu * mu;
      float rs = rsqrtf(var + 1e-5f);
#pragma unroll
      for (int i = 0; i < 3; ++i) {
        const int e = 2 * (64 * i + lane);
        float2 gg = *(const float2*)&g[e];
        float2 bb = *(const float2*)&b[e];
        x32[xbase + 64 * i + lane] = pack2(v[2 * i], v[2 * i + 1]);
        o32[xbase + 64 * i + lane] =
            pack2((v[2 * i] - mu) * rs * gg.x + bb.x,
                  (v[2 * i + 1] - mu) * rs * gg.y + bb.y);
      }
    }
    __syncthreads();                              // LDS reuse for next half
  }
}

// ------------- MFMA attention v2: 8 waves, K+V in LDS, balanced q-tiles -------------
// qk: [R][768] bf16 (q|k, each hh*64+d). vt: [384][R] bf16 (V^T). o: [R][384] bf16.
// wave w owns q-tiles {w, 15-w}: 17 QK-tiles and 9 PV-iters per wave for every w.
__global__ __launch_bounds__(512, 4)
void attn_kernel(const ushort_t* __restrict__ qk, const ushort_t* __restrict__ vt,
                 ushort_t* __restrict__ o, int R) {
  __shared__ ushort_t Ks[16384];             // 32KB swizzled: byte s*128 + (db^((s&7)<<4))
  __shared__ ushort_t Vs[16512];             // 33KB V^T rows, stride 258 ushorts (pad 2)
  __shared__ ushort_t Pb[8][640];            // per-wave P, 80 B rows
  const int tid = threadIdx.x;
  const int w = tid >> 6, lane = tid & 63;
  const int seq = blockIdx.x / HH, hh = blockIdx.x % HH;
  const int brow = seq * TT;

  // stage K: global_load_lds, pre-swizzled source (XOR involution on 16B slots)
  {
    const ushort_t* kbase = qk + (size_t)brow * 768 + 384 + hh * 64;
#pragma unroll
    for (int cc = 0; cc < 4; ++cc) {
      const int ci = cc * 512 + tid;
      const int s = ci >> 3, j = ci & 7;
      const int srcb = (j * 16) ^ ((s & 7) << 4);
      gload_lds16(kbase + (size_t)s * 768 + (srcb >> 1), Ks + cc * 4096 + w * 512);
    }
  }
  // stage V^T: global -> reg -> padded LDS (pad legal: reg-staged, not gload_lds)
  {
    s16x8 vreg[4];
    int vidx[4];
#pragma unroll
    for (int t2 = 0; t2 < 4; ++t2) {
      const int ci = t2 * 512 + tid;
      const int d = ci >> 5, c2 = ci & 31;
      vidx[t2] = d * 258 + c2 * 8;
      vreg[t2] = *(const s16x8*)(vt + (size_t)(hh * 64 + d) * R + brow + c2 * 8);
    }
#pragma unroll
    for (int t2 = 0; t2 < 4; ++t2)
      *(s16x8*)(Vs + vidx[t2]) = vreg[t2];
  }
  __syncthreads();

  const int r = lane & 15, g = lane >> 4;
  ushort_t* pw = &Pb[w][0];

#pragma unroll
  for (int qti = 0; qti < 2; ++qti) {
    const int qt = qti ? (15 - w) : w;
    const int q0 = qt << 4;
    const int n_st = qt + 1;                        // s-tiles needed (diag = last)
    const ushort_t* qrow = qk + (size_t)(brow + q0 + r) * 768 + hh * 64 + g * 8;
    const s16x8 qa0 = *(const s16x8*)qrow;          // d in [g*8, g*8+8) of [0,32)
    const s16x8 qa1 = *(const s16x8*)(qrow + 32);   // d-half 2

    f32x4 S[16];
#pragma unroll
    for (int st = 0; st < 16; ++st) {
      if (st < n_st) {
        const int srow = st * 16 + r;
        const int sw = (srow & 7) << 4;
        const s16x8 kb0 = *(const s16x8*)(Ks + ((srow * 128 + ((g * 16) ^ sw)) >> 1));
        const s16x8 kb1 = *(const s16x8*)(Ks + ((srow * 128 + ((64 + g * 16) ^ sw)) >> 1));
        f32x4 t = {0.f, 0.f, 0.f, 0.f};
        t = __builtin_amdgcn_mfma_f32_16x16x32_bf16(qa0, kb0, t, 0, 0, 0);
        t = __builtin_amdgcn_mfma_f32_16x16x32_bf16(qa1, kb1, t, 0, 0, 0);
        if (st == n_st - 1) {                       // diagonal tile mask
#pragma unroll
          for (int j = 0; j < 4; ++j)
            t[j] = (r <= g * 4 + j) ? t[j] : -1e30f;
        }
        S[st] = t;
      }
    }

    float mrow[4] = {-1e30f, -1e30f, -1e30f, -1e30f};
#pragma unroll
    for (int st = 0; st < 16; ++st)
      if (st < n_st) {
#pragma unroll
        for (int j = 0; j < 4; ++j) mrow[j] = fmaxf(mrow[j], S[st][j]);
      }
#pragma unroll
    for (int j = 0; j < 4; ++j) {
      float m = mrow[j];
      m = fmaxf(m, __shfl_xor(m, 1));
      m = fmaxf(m, __shfl_xor(m, 2));
      m = fmaxf(m, __shfl_xor(m, 4));
      m = fmaxf(m, __shfl_xor(m, 8));
      mrow[j] = m;
    }

    float rsum[4] = {0.f, 0.f, 0.f, 0.f};
    f32x4 O[4] = {f32x4{0,0,0,0}, f32x4{0,0,0,0}, f32x4{0,0,0,0}, f32x4{0,0,0,0}};
    const int n_sc = (n_st + 1) >> 1;
#pragma unroll
    for (int sc = 0; sc < 8; ++sc) {
      if (sc < n_sc) {
        // write P tiles 2sc, 2sc+1 (unnormalized bf16; zeros for invalid)
#pragma unroll
        for (int tt = 0; tt < 2; ++tt) {
          const int st = sc * 2 + tt;
#pragma unroll
          for (int j = 0; j < 4; ++j) {
            float p = 0.f;
            if (st < n_st) p = __expf((S[st][j] - mrow[j]) * 0.125f);
            rsum[j] += p;
            pw[(g * 4 + j) * 40 + tt * 16 + r] = f2b(p);
          }
        }
        const s16x8 pa = *(const s16x8*)(pw + r * 40 + g * 8);   // compiler lgkmcnt
#pragma unroll
        for (int dt = 0; dt < 4; ++dt) {
          const s16x8 vb = *(const s16x8*)(Vs + (dt * 16 + r) * 258 + sc * 32 + g * 8);
          O[dt] = __builtin_amdgcn_mfma_f32_16x16x32_bf16(pa, vb, O[dt], 0, 0, 0);
        }
      }
    }

#pragma unroll
    for (int j = 0; j < 4; ++j) {
      float s = rsum[j];
      s += __shfl_xor(s, 1);
      s += __shfl_xor(s, 2);
      s += __shfl_xor(s, 4);
      s += __shfl_xor(s, 8);
      rsum[j] = 1.f / s;
    }
    ushort_t* obase = o + (size_t)(brow + q0 + g * 4) * 384 + hh * 64 + r;
#pragma unroll
    for (int j = 0; j < 4; ++j)
#pragma unroll
      for (int dt = 0; dt < 4; ++dt)
        obase[(size_t)j * 384 + dt * 16] = f2b(O[dt][j] * rsum[j]);
  }
}

// -------- loss: grid-stride rows, block-reduce, one atomic per block --------
__global__ __launch_bounds__(256)
void loss_kernel(const float* __restrict__ logits, const int* __restrict__ targets,
                 float* __restrict__ loss_acc, int R) {
  __shared__ float red[4];
  int wid = threadIdx.x >> 6, lane = threadIdx.x & 63;
  float lsum = 0.f;
  for (int r = blockIdx.x * 4 + wid; r < R; r += gridDim.x * 4) {
    const float* lrow = logits + (size_t)r * VV;
    float v = lrow[lane];
    float e64 = lrow[64];
    float m = fmaxf(v, e64);
#pragma unroll
    for (int off = 32; off; off >>= 1) m = fmaxf(m, __shfl_xor(m, off));
    float s = expf(v - m);
#pragma unroll
    for (int off = 32; off; off >>= 1) s += __shfl_xor(s, off);
    s += expf(e64 - m);
    float lse = m + logf(s);
    int t = targets[r];
    float tv = (t < 64) ? __shfl(v, t) : e64;
    lsum += lse - tv;
  }
  if (lane == 0) red[wid] = lsum;
  __syncthreads();
  if (threadIdx.x == 0)
    atomicAdd(loss_acc, (red[0] + red[1] + red[2] + red[3]) * (1.f / BT));
}

// ---------------- launcher ----------------
extern "C" void kernel_launch(void* const* d_in, const int* in_sizes, int n_in,
                              void* d_out, int out_size, void* d_ws, size_t ws_size,
                              hipStream_t stream) {
  const int* inputs = (const int*)d_in[0];
  const int* targets = (const int*)d_in[1];
  const float* tok_emb = (const float*)d_in[2];
  const float* pos_emb = (const float*)d_in[3];
  const float* Wq = (const float*)d_in[4];
  const float* Wk = (const float*)d_in[5];
  const float* Wv = (const float*)d_in[6];
  const float* Wo = (const float*)d_in[7];
  const float* bo = (const float*)d_in[8];
  const float* ln1_g = (const float*)d_in[9];
  const float* ln1_b = (const float*)d_in[10];
  const float* W1 = (const float*)d_in[11];
  const float* b1 = (const float*)d_in[12];
  const float* W2 = (const float*)d_in[13];
  const float* b2 = (const float*)d_in[14];
  const float* ln2_g = (const float*)d_in[15];
  const float* ln2_b = (const float*)d_in[16];
  const float* lnf_g = (const float*)d_in[17];
  const float* lnf_b = (const float*)d_in[18];
  const float* Wh = (const float*)d_in[19];
  const float* bh = (const float*)d_in[20];

  float* logits = (float*)d_out;
  float* loss = logits + (size_t)BT * VV;

  auto al = [](size_t b) { return (b + 255) & ~(size_t)255; };
  const size_t wq_b = al((size_t)LL * 1152 * 384 * 2);
  const size_t wo_b = al((size_t)LL * 384 * 384 * 2);
  const size_t w1_b = al((size_t)LL * 1536 * 384 * 2);
  const size_t wh_b = al((size_t)128 * 384 * 2);
  const size_t wfix = wq_b + wo_b + 2 * w1_b + wh_b;

  int c = BB;                                  // c=256: round-7 A/B showed chunking loses
  while (c > 1 && wfix + (size_t)c * 256 * 6144 > ws_size) c >>= 1;
  const int R = c * TT;
  const int nch = BB / c;

  char* p = (char*)d_ws;
  ushort_t* wqkv = (ushort_t*)p; p += wq_b;
  ushort_t* wot  = (ushort_t*)p; p += wo_b;
  ushort_t* w1t  = (ushort_t*)p; p += w1_b;
  ushort_t* w2t  = (ushort_t*)p; p += w1_b;
  ushort_t* whb  = (ushort_t*)p; p += wh_b;
  ushort_t* x = (ushort_t*)p;    p += (size_t)R * 768;    // [R,384] bf16 residual
  ushort_t* hb = (ushort_t*)p;   p += (size_t)R * 768;    // [R,384] bf16
  ushort_t* ob = (ushort_t*)p;   p += (size_t)R * 768;    // [R,384] bf16
  ushort_t* un = (ushort_t*)p;                            // R*3072 B union
  ushort_t* qkb = un;                                     // [R,768] bf16
  ushort_t* vtb = un + (size_t)R * 768;                   // [384,R] bf16
  ushort_t* midb = un;                                    // [R,1536] bf16

  hipMemsetAsync(loss, 0, 4, stream);
  pack_qkv<<<LL * 1152 * 384 / 256, 256, 0, stream>>>(Wq, Wk, Wv, wqkv);
  pack_wt<<<LL * 384 * 384 / 256, 256, 0, stream>>>(Wo, wot, 384, 384);
  pack_wt<<<LL * 384 * 1536 / 256, 256, 0, stream>>>(W1, w1t, 384, 1536);
  pack_wt<<<LL * 1536 * 384 / 256, 256, 0, stream>>>(W2, w2t, 1536, 384);
  pack_head<<<128 * 384 / 256, 256, 0, stream>>>(Wh, whb);

  const int my = R / 128;
  for (int ch = 0; ch < nch; ++ch) {
    const size_t r0 = (size_t)ch * R;
    embed_ln<<<R / 4, 256, 0, stream>>>(inputs + r0, tok_emb, pos_emb,
                                        ln1_g, ln1_b, x, hb);
    for (int l = 0; l < LL; ++l) {
      gemm_bf16<3, false, false><<<9 * my, 256, 0, stream>>>(
          hb, wqkv + (size_t)l * 1152 * 384, nullptr, qkb, nullptr, vtb, R, 1152, 384, 9);
      attn_kernel<<<c * HH, 512, 0, stream>>>(qkb, vtb, ob, R);
      gemm_resln<<<my, 512, 0, stream>>>(                         // Wo + res + LN(ln2)
          ob, wot + (size_t)l * 384 * 384, bo + l * EE, x,
          ln2_g + l * EE, ln2_b + l * EE, hb, R, 384);
      gemm_bf16<0, true, true><<<12 * my, 256, 0, stream>>>(
          hb, w1t + (size_t)l * 1536 * 384, b1 + l * FF, midb, nullptr, nullptr, R, 1536, 384, 12);
      const float* ng = (l + 1 < LL) ? ln1_g + (l + 1) * EE : lnf_g;
      const float* nb = (l + 1 < LL) ? ln1_b + (l + 1) * EE : lnf_b;
      gemm_resln<<<my, 512, 0, stream>>>(                         // FFN2 + res + LN(next)
          midb, w2t + (size_t)l * 384 * 1536, b2 + l * EE, x, ng, nb, hb, R, 1536);
    }
    gemm_bf16<2, true, false><<<1 * my, 256, 0, stream>>>(
        hb, whb, bh, nullptr, logits + r0 * VV, nullptr, R, 128, 384, 1);
    loss_kernel<<<1024, 256, 0, stream>>>(logits + r0 * VV, targets + r0, loss, R);
  }
}

// Round 13
// 2827.942 us; speedup vs baseline: 2.4058x; 2.4058x over previous
//
#include <hip/hip_runtime.h>
#include <math.h>

#define LL 6
#define HH 6
#define EE 384
#define FF 1536
#define TT 256
#define BB 256
#define VV 65
constexpr int BT = BB * TT;                 // 65536 rows total

typedef __attribute__((ext_vector_type(8))) short s16x8;   // 8 bf16 (4 VGPR)
typedef __attribute__((ext_vector_type(4))) float f32x4;
typedef __attribute__((ext_vector_type(2))) unsigned int u32x2;
typedef unsigned int uint;
typedef unsigned short ushort_t;

__device__ __forceinline__ float uaf(uint u) { union { uint u; float f; } c; c.u = u; return c.f; }
__device__ __forceinline__ ushort_t f2b(float f) {
  union { float f; uint u; } c; c.f = f;
  uint r = c.u + 0x7fffu + ((c.u >> 16) & 1u);          // RNE
  return (ushort_t)(r >> 16);
}
__device__ __forceinline__ float b2f(ushort_t b) { return uaf((uint)b << 16); }
__device__ __forceinline__ float blo(uint u) { return uaf(u << 16); }
__device__ __forceinline__ float bhi(uint u) { return uaf(u & 0xffff0000u); }
__device__ __forceinline__ uint pack2(float a, float b) {
  return (uint)f2b(a) | ((uint)f2b(b) << 16);
}

__device__ __forceinline__ void gload_lds16(const void* g, void* l) {
  __builtin_amdgcn_global_load_lds(
      (const __attribute__((address_space(1))) unsigned int*)g,
      (__attribute__((address_space(3))) unsigned int*)l, 16, 0, 0);
}

// ------- embed + layer-0 LN fused: x = bf16(tok+pos); hb = LN(x) -------
__global__ __launch_bounds__(256)
void embed_ln(const int* __restrict__ inp, const float* __restrict__ tok,
              const float* __restrict__ pos, const float* __restrict__ g,
              const float* __restrict__ b, ushort_t* __restrict__ x,
              ushort_t* __restrict__ outp) {
  int wid = threadIdx.x >> 6, lane = threadIdx.x & 63;
  int row = blockIdx.x * 4 + wid;
  int t = row % TT;
  int tk = inp[row];
  const float* tr = tok + (size_t)tk * EE;
  const float* pr = pos + (size_t)t * EE;
  float v[6];
  float s = 0.f, s2 = 0.f;
#pragma unroll
  for (int i = 0; i < 3; ++i) {
    int e = 2 * lane + 128 * i;
    float2 a = *(const float2*)&tr[e];
    float2 p2 = *(const float2*)&pr[e];
    v[2 * i] = a.x + p2.x;
    v[2 * i + 1] = a.y + p2.y;
    s += v[2 * i] + v[2 * i + 1];
    s2 += v[2 * i] * v[2 * i] + v[2 * i + 1] * v[2 * i + 1];
  }
#pragma unroll
  for (int off = 32; off; off >>= 1) {
    s += __shfl_xor(s, off);
    s2 += __shfl_xor(s2, off);
  }
  float mu = s * (1.f / EE);
  float var = s2 * (1.f / EE) - mu * mu;
  float rs = rsqrtf(var + 1e-5f);
  uint* x32 = (uint*)x;
  uint* o32 = (uint*)outp;
#pragma unroll
  for (int i = 0; i < 3; ++i) {
    int e = 2 * lane + 128 * i;
    float2 gg = *(const float2*)&g[e];
    float2 bb = *(const float2*)&b[e];
    int slot = row * 192 + lane + 64 * i;
    x32[slot] = pack2(v[2 * i], v[2 * i + 1]);
    o32[slot] = pack2((v[2 * i] - mu) * rs * gg.x + bb.x,
                      (v[2 * i + 1] - mu) * rs * gg.y + bb.y);
  }
}

// ------- pack QKV weights: [l][h][e][d] f32 -> bf16 [l][n=1152][k=384] -------
__global__ __launch_bounds__(256)
void pack_qkv(const float* __restrict__ Wq, const float* __restrict__ Wk,
              const float* __restrict__ Wv, ushort_t* __restrict__ dst) {
  int idx = blockIdx.x * 256 + threadIdx.x;
  int l = idx / (1152 * 384);
  int r = idx % (1152 * 384);
  int n = r / 384;
  int k = r % 384;
  int which = n / 384;                            // 0:q 1:k 2:v
  int hd = n % 384;
  int h = hd >> 6, d = hd & 63;
  const float* src = which == 0 ? Wq : (which == 1 ? Wk : Wv);
  dst[idx] = f2b(src[((size_t)(l * HH + h) * EE + k) * 64 + d]);
}

// ------- pack generic weight: [l][k][n] f32 -> bf16 [l][n][k] -------
__global__ __launch_bounds__(256)
void pack_wt(const float* __restrict__ src, ushort_t* __restrict__ dst, int Kd, int Nd) {
  int idx = blockIdx.x * 256 + threadIdx.x;
  int l = idx / (Kd * Nd);
  int r = idx % (Kd * Nd);
  int n = r / Kd;
  int k = r % Kd;
  dst[idx] = f2b(src[((size_t)l * Kd + k) * Nd + n]);
}

// ------- pack head: Wh [384][65] f32 -> bf16 [128][384], zero-pad -------
__global__ __launch_bounds__(256)
void pack_head(const float* __restrict__ Wh, ushort_t* __restrict__ dst) {
  int idx = blockIdx.x * 256 + threadIdx.x;
  int n = idx / 384, k = idx % 384;
  dst[idx] = (n < VV) ? f2b(Wh[(size_t)k * VV + n]) : (ushort_t)0;
}

// ------------- bf16 MFMA GEMM, double-buffered, counted-vmcnt pipeline -------------
// A[M,K] bf16, Wt[N,K] bf16 (W^T). M%128==0, N%128==0, K%32==0.
// MODE 0: Cb[M,N] bf16 = (relu)(acc+bias)   [LDS-coalesced writes]
// MODE 2: head — Cf f32, stride VV, cols<VV
// MODE 3: qkv split — cols<768 -> Cb stride 768 (coalesced); cols>=768 -> Cv[col-768][M]
template <int MODE, bool BIAS, bool RELU>
__global__ __launch_bounds__(256)
void gemm_bf16(const ushort_t* __restrict__ A, const ushort_t* __restrict__ Wt,
               const float* __restrict__ bias, ushort_t* __restrict__ Cb,
               float* __restrict__ Cf, ushort_t* __restrict__ Cv,
               int M, int N, int K, int nx) {
  __shared__ ushort_t sm[16896];                  // staging 2x(4096+4096) | ep 128x132
  ushort_t* As = sm;
  ushort_t* Bs = sm + 8192;
  const int tid = threadIdx.x;

  int bid = blockIdx.x;
  {
    const int nwg = gridDim.x;
    const int q = nwg >> 3, rr = nwg & 7;
    const int xcd = bid & 7, within = bid >> 3;
    bid = (xcd < rr ? xcd * (q + 1) : rr * (q + 1) + (xcd - rr) * q) + within;
  }
  const int bn = (bid % nx) * 128;
  const int bm = (bid / nx) * 128;

  const int w = tid >> 6, lane = tid & 63;
  const int wr = (w >> 1) * 64, wc = (w & 1) * 64;
  const int fr = lane & 15, fq = lane >> 4;

  // staging addressing (slot-XOR swizzle, round-3-verified)
  const int rp = lane >> 2;
  const int fqs = (lane & 3) ^ ((rp >> 1) & 3);
  const ushort_t* Ag0 = A + (size_t)(bm + w * 16 + rp) * K + fqs * 8;
  const ushort_t* Ag1 = Ag0 + (size_t)64 * K;
  const ushort_t* Bg0 = Wt + (size_t)(bn + w * 16 + rp) * K + fqs * 8;
  const ushort_t* Bg1 = Bg0 + (size_t)64 * K;

  const int slotr = (fq ^ ((fr >> 1) & 3)) * 8;
  const ushort_t* Ard = As + (wr + fr) * 32 + slotr;
  const ushort_t* Brd = Bs + (wc + fr) * 32 + slotr;

  const int nt = K >> 5;
  auto STAGE = [&](int kt, int b) {
    const int k0 = kt << 5;
    const int bo = b << 12;                       // 4096 elems per buffer
    gload_lds16(Ag0 + k0, As + bo + (w * 16) * 32);
    gload_lds16(Ag1 + k0, As + bo + (64 + w * 16) * 32);
    gload_lds16(Bg0 + k0, Bs + bo + (w * 16) * 32);
    gload_lds16(Bg1 + k0, Bs + bo + (64 + w * 16) * 32);
  };

  f32x4 acc[4][4] = {};
  STAGE(0, 0);

  for (int t = 0; t < nt; ++t) {
    const int bo = (t & 1) << 12;
    if (t + 1 < nt) {
      STAGE(t + 1, (t & 1) ^ 1);                  // next tile's 4 loads in flight
      asm volatile("s_waitcnt vmcnt(4)" ::: "memory");   // wait buf t only
    } else {
      asm volatile("s_waitcnt vmcnt(0)" ::: "memory");
    }
    __builtin_amdgcn_s_barrier();                 // all waves: buf t written
    __builtin_amdgcn_sched_barrier(0);
    s16x8 afr[4], bfr[4];
#pragma unroll
    for (int m = 0; m < 4; ++m) afr[m] = *(const s16x8*)(Ard + bo + m * 512);
#pragma unroll
    for (int n = 0; n < 4; ++n) bfr[n] = *(const s16x8*)(Brd + bo + n * 512);
#pragma unroll
    for (int m = 0; m < 4; ++m)
#pragma unroll
      for (int n = 0; n < 4; ++n)
        acc[m][n] = __builtin_amdgcn_mfma_f32_16x16x32_bf16(afr[m], bfr[n], acc[m][n], 0, 0, 0);
    __builtin_amdgcn_sched_barrier(0);
    __builtin_amdgcn_s_barrier();                 // reads done before buf overwrite
  }

  // epilogue: D row = (lane>>4)*4 + j, col = lane&15
  if constexpr (MODE == 0 || MODE == 3) {
    if (MODE == 3 && bn >= 768) {                 // V region: write V^T [384][M]
      const int r0 = bm + wr + fq * 4;
      const int c0 = bn + wc + fr;
#pragma unroll
      for (int n = 0; n < 4; ++n) {
        const int col = c0 + n * 16 - 768;
#pragma unroll
        for (int m = 0; m < 4; ++m) {
          const int row = r0 + m * 16;
          uint lo = (uint)f2b(acc[m][n][0]) | ((uint)f2b(acc[m][n][1]) << 16);
          uint hi = (uint)f2b(acc[m][n][2]) | ((uint)f2b(acc[m][n][3]) << 16);
          *(u32x2*)&Cv[(size_t)col * M + row] = u32x2{lo, hi};
        }
      }
      return;
    }
    // LDS-bounce coalesced store: tile -> ep[128][132] -> 16B/lane rows
    const int ostride = (MODE == 3) ? 768 : N;
#pragma unroll
    for (int n = 0; n < 4; ++n) {
      const int col = wc + n * 16 + fr;
      const float bv = BIAS ? bias[bn + col] : 0.f;
#pragma unroll
      for (int m = 0; m < 4; ++m) {
        const int row = wr + m * 16 + fq * 4;
#pragma unroll
        for (int j = 0; j < 4; ++j) {
          float vv = acc[m][n][j] + bv;
          if constexpr (RELU) vv = fmaxf(vv, 0.f);
          sm[(row + j) * 132 + col] = f2b(vv);    // fq -> +8 banks: conflict-free
        }
      }
    }
    __syncthreads();
    const int rr2 = tid >> 4, cb = (tid & 15) * 8;
#pragma unroll
    for (int pp = 0; pp < 8; ++pp) {
      const int row = pp * 16 + rr2;
      s16x8 v8 = *(const s16x8*)(sm + row * 132 + cb);
      *(s16x8*)(Cb + (size_t)(bm + row) * ostride + bn + cb) = v8;
    }
    return;
  }
  // MODE 2: head, f32 logits stride VV, cols < VV
  const int r0 = bm + wr + fq * 4;
  const int c0 = bn + wc + fr;
#pragma unroll
  for (int n = 0; n < 4; ++n) {
    const int col = c0 + n * 16;
    if (col >= VV) continue;
    const float bv = BIAS ? bias[col] : 0.f;
#pragma unroll
    for (int m = 0; m < 4; ++m) {
      const int row = r0 + m * 16;
#pragma unroll
      for (int j = 0; j < 4; ++j)
        Cf[(size_t)(row + j) * VV + col] = acc[m][n][j] + bv;
    }
  }
}

// ------- fused GEMM(N=384) + residual + LayerNorm (coalesced epilogue v2) -------
// delta = A@Wt^T + bias; v = x + delta; x <- v; out <- LN(v; g, b).
// 512 threads, BM=128, BN=384. 8 waves = 2M x 4N, wave tile 64x96.
// NOTE: no min-waves in launch_bounds — acc[4][6]=96 VGPR + frags needs ~160 VGPR;
// (512,4)'s 128-VGPR cap spilled accumulators to scratch (round-12: 862MB writes).
__global__ __launch_bounds__(512)
void gemm_resln(const ushort_t* __restrict__ A, const ushort_t* __restrict__ Wt,
                const float* __restrict__ bias, ushort_t* __restrict__ x,
                const float* __restrict__ g, const float* __restrict__ b,
                ushort_t* __restrict__ outp, int M, int K) {
  __shared__ ushort_t sm[32768];                  // A 2x4096 | B 2x12288 (64 KB)
  ushort_t* As = sm;
  ushort_t* Bs = sm + 8192;
  const int tid = threadIdx.x;

  int bid = blockIdx.x;
  {
    const int nwg = gridDim.x;
    const int q = nwg >> 3, rm = nwg & 7;
    const int xcd = bid & 7, within = bid >> 3;
    bid = (xcd < rm ? xcd * (q + 1) : rm * (q + 1) + (xcd - rm) * q) + within;
  }
  const int bm = bid * 128;

  const int w = tid >> 6, lane = tid & 63;
  const int wm = w >> 2, wn = w & 3;
  const int wr = wm * 64, wc = wn * 96;
  const int fr = lane & 15, fq = lane >> 4;

  const int rp = lane >> 2;
  const int fqs = (lane & 3) ^ ((rp >> 1) & 3);
  const ushort_t* Ag = A + (size_t)(bm + w * 16 + rp) * K + fqs * 8;
  const ushort_t* Bg = Wt + (size_t)(w * 16 + rp) * K + fqs * 8;

  const int slotr = (fq ^ ((fr >> 1) & 3)) * 8;
  const ushort_t* Ard = As + (wr + fr) * 32 + slotr;
  const ushort_t* Brd = Bs + (wc + fr) * 32 + slotr;

  const int nt = K >> 5;
  auto STAGE = [&](int kt, int bsel) {
    const int k0 = kt << 5;
    gload_lds16(Ag + k0, As + (bsel ? 4096 : 0) + (w * 16) * 32);
    const int bo = bsel ? 12288 : 0;
#pragma unroll
    for (int gi = 0; gi < 3; ++gi)
      gload_lds16(Bg + (size_t)(128 * gi) * K + k0,
                  Bs + bo + (gi * 128 + w * 16) * 32);
  };

  f32x4 acc[4][6] = {};
  STAGE(0, 0);

  for (int t = 0; t < nt; ++t) {
    const int aob = (t & 1) ? 4096 : 0;
    const int bob = (t & 1) ? 12288 : 0;
    if (t + 1 < nt) {
      STAGE(t + 1, (t & 1) ^ 1);                  // 4 loads/thread in flight
      asm volatile("s_waitcnt vmcnt(4)" ::: "memory");
    } else {
      asm volatile("s_waitcnt vmcnt(0)" ::: "memory");
    }
    __builtin_amdgcn_s_barrier();
    __builtin_amdgcn_sched_barrier(0);
    s16x8 afr[4], bfr[6];
#pragma unroll
    for (int m = 0; m < 4; ++m) afr[m] = *(const s16x8*)(Ard + aob + m * 512);
#pragma unroll
    for (int n = 0; n < 6; ++n) bfr[n] = *(const s16x8*)(Brd + bob + n * 512);
#pragma unroll
    for (int m = 0; m < 4; ++m)
#pragma unroll
      for (int n = 0; n < 6; ++n)
        acc[m][n] = __builtin_amdgcn_mfma_f32_16x16x32_bf16(afr[m], bfr[n], acc[m][n], 0, 0, 0);
    __builtin_amdgcn_sched_barrier(0);
    __builtin_amdgcn_s_barrier();
  }

  // epilogue: two 64-row halves through LDS tile [64][388] bf16.
  // LN phase uses ln_res-verified coalesced indexing: uint slot = row*192 + 64*i + lane.
  uint* x32 = (uint*)x;
  uint* o32 = (uint*)outp;
  const uint* smu = (const uint*)sm;
#pragma unroll
  for (int h = 0; h < 2; ++h) {
    if (wm == h) {                                // this half's owner waves write delta
#pragma unroll
      for (int n = 0; n < 6; ++n) {
        const int col = wc + n * 16 + fr;
        const float bv = bias[col];
#pragma unroll
        for (int m = 0; m < 4; ++m) {
          const int rr = m * 16 + fq * 4;
#pragma unroll
          for (int j = 0; j < 4; ++j)
            sm[(rr + j) * 388 + col] = f2b(acc[m][n][j] + bv);
        }
      }
    }
    __syncthreads();
    // each wave finishes 8 rows (delta from LDS, x from global; all coalesced)
#pragma unroll
    for (int rr = 0; rr < 8; ++rr) {
      const int rih = w * 8 + rr;
      const int row = h * 64 + rih;
      const size_t xbase = (size_t)(bm + row) * 192;
      float v[6];
      float s = 0.f, s2 = 0.f;
#pragma unroll
      for (int i = 0; i < 3; ++i) {
        uint du = smu[rih * 194 + 64 * i + lane];
        uint xu = x32[xbase + 64 * i + lane];
        v[2 * i] = blo(du) + blo(xu);
        v[2 * i + 1] = bhi(du) + bhi(xu);
        s += v[2 * i] + v[2 * i + 1];
        s2 += v[2 * i] * v[2 * i] + v[2 * i + 1] * v[2 * i + 1];
      }
#pragma unroll
      for (int off = 32; off; off >>= 1) {
        s += __shfl_xor(s, off);
        s2 += __shfl_xor(s2, off);
      }
      float mu = s * (1.f / EE);
      float var = s2 * (1.f / EE) - mu * mu;
      float rs = rsqrtf(var + 1e-5f);
#pragma unroll
      for (int i = 0; i < 3; ++i) {
        const int e = 2 * (64 * i + lane);
        float2 gg = *(const float2*)&g[e];
        float2 bb = *(const float2*)&b[e];
        x32[xbase + 64 * i + lane] = pack2(v[2 * i], v[2 * i + 1]);
        o32[xbase + 64 * i + lane] =
            pack2((v[2 * i] - mu) * rs * gg.x + bb.x,
                  (v[2 * i + 1] - mu) * rs * gg.y + bb.y);
      }
    }
    __syncthreads();                              // LDS reuse for next half
  }
}

// ------------- MFMA attention v2: 8 waves, K+V in LDS, balanced q-tiles -------------
// qk: [R][768] bf16 (q|k, each hh*64+d). vt: [384][R] bf16 (V^T). o: [R][384] bf16.
// wave w owns q-tiles {w, 15-w}: 17 QK-tiles and 9 PV-iters per wave for every w.
__global__ __launch_bounds__(512, 4)
void attn_kernel(const ushort_t* __restrict__ qk, const ushort_t* __restrict__ vt,
                 ushort_t* __restrict__ o, int R) {
  __shared__ ushort_t Ks[16384];             // 32KB swizzled: byte s*128 + (db^((s&7)<<4))
  __shared__ ushort_t Vs[16512];             // 33KB V^T rows, stride 258 ushorts (pad 2)
  __shared__ ushort_t Pb[8][640];            // per-wave P, 80 B rows
  const int tid = threadIdx.x;
  const int w = tid >> 6, lane = tid & 63;
  const int seq = blockIdx.x / HH, hh = blockIdx.x % HH;
  const int brow = seq * TT;

  // stage K: global_load_lds, pre-swizzled source (XOR involution on 16B slots)
  {
    const ushort_t* kbase = qk + (size_t)brow * 768 + 384 + hh * 64;
#pragma unroll
    for (int cc = 0; cc < 4; ++cc) {
      const int ci = cc * 512 + tid;
      const int s = ci >> 3, j = ci & 7;
      const int srcb = (j * 16) ^ ((s & 7) << 4);
      gload_lds16(kbase + (size_t)s * 768 + (srcb >> 1), Ks + cc * 4096 + w * 512);
    }
  }
  // stage V^T: global -> reg -> padded LDS (pad legal: reg-staged, not gload_lds)
  {
    s16x8 vreg[4];
    int vidx[4];
#pragma unroll
    for (int t2 = 0; t2 < 4; ++t2) {
      const int ci = t2 * 512 + tid;
      const int d = ci >> 5, c2 = ci & 31;
      vidx[t2] = d * 258 + c2 * 8;
      vreg[t2] = *(const s16x8*)(vt + (size_t)(hh * 64 + d) * R + brow + c2 * 8);
    }
#pragma unroll
    for (int t2 = 0; t2 < 4; ++t2)
      *(s16x8*)(Vs + vidx[t2]) = vreg[t2];
  }
  __syncthreads();

  const int r = lane & 15, g = lane >> 4;
  ushort_t* pw = &Pb[w][0];

#pragma unroll
  for (int qti = 0; qti < 2; ++qti) {
    const int qt = qti ? (15 - w) : w;
    const int q0 = qt << 4;
    const int n_st = qt + 1;                        // s-tiles needed (diag = last)
    const ushort_t* qrow = qk + (size_t)(brow + q0 + r) * 768 + hh * 64 + g * 8;
    const s16x8 qa0 = *(const s16x8*)qrow;          // d in [g*8, g*8+8) of [0,32)
    const s16x8 qa1 = *(const s16x8*)(qrow + 32);   // d-half 2

    f32x4 S[16];
#pragma unroll
    for (int st = 0; st < 16; ++st) {
      if (st < n_st) {
        const int srow = st * 16 + r;
        const int sw = (srow & 7) << 4;
        const s16x8 kb0 = *(const s16x8*)(Ks + ((srow * 128 + ((g * 16) ^ sw)) >> 1));
        const s16x8 kb1 = *(const s16x8*)(Ks + ((srow * 128 + ((64 + g * 16) ^ sw)) >> 1));
        f32x4 t = {0.f, 0.f, 0.f, 0.f};
        t = __builtin_amdgcn_mfma_f32_16x16x32_bf16(qa0, kb0, t, 0, 0, 0);
        t = __builtin_amdgcn_mfma_f32_16x16x32_bf16(qa1, kb1, t, 0, 0, 0);
        if (st == n_st - 1) {                       // diagonal tile mask
#pragma unroll
          for (int j = 0; j < 4; ++j)
            t[j] = (r <= g * 4 + j) ? t[j] : -1e30f;
        }
        S[st] = t;
      }
    }

    float mrow[4] = {-1e30f, -1e30f, -1e30f, -1e30f};
#pragma unroll
    for (int st = 0; st < 16; ++st)
      if (st < n_st) {
#pragma unroll
        for (int j = 0; j < 4; ++j) mrow[j] = fmaxf(mrow[j], S[st][j]);
      }
#pragma unroll
    for (int j = 0; j < 4; ++j) {
      float m = mrow[j];
      m = fmaxf(m, __shfl_xor(m, 1));
      m = fmaxf(m, __shfl_xor(m, 2));
      m = fmaxf(m, __shfl_xor(m, 4));
      m = fmaxf(m, __shfl_xor(m, 8));
      mrow[j] = m;
    }

    float rsum[4] = {0.f, 0.f, 0.f, 0.f};
    f32x4 O[4] = {f32x4{0,0,0,0}, f32x4{0,0,0,0}, f32x4{0,0,0,0}, f32x4{0,0,0,0}};
    const int n_sc = (n_st + 1) >> 1;
#pragma unroll
    for (int sc = 0; sc < 8; ++sc) {
      if (sc < n_sc) {
        // write P tiles 2sc, 2sc+1 (unnormalized bf16; zeros for invalid)
#pragma unroll
        for (int tt = 0; tt < 2; ++tt) {
          const int st = sc * 2 + tt;
#pragma unroll
          for (int j = 0; j < 4; ++j) {
            float p = 0.f;
            if (st < n_st) p = __expf((S[st][j] - mrow[j]) * 0.125f);
            rsum[j] += p;
            pw[(g * 4 + j) * 40 + tt * 16 + r] = f2b(p);
          }
        }
        const s16x8 pa = *(const s16x8*)(pw + r * 40 + g * 8);   // compiler lgkmcnt
#pragma unroll
        for (int dt = 0; dt < 4; ++dt) {
          const s16x8 vb = *(const s16x8*)(Vs + (dt * 16 + r) * 258 + sc * 32 + g * 8);
          O[dt] = __builtin_amdgcn_mfma_f32_16x16x32_bf16(pa, vb, O[dt], 0, 0, 0);
        }
      }
    }

#pragma unroll
    for (int j = 0; j < 4; ++j) {
      float s = rsum[j];
      s += __shfl_xor(s, 1);
      s += __shfl_xor(s, 2);
      s += __shfl_xor(s, 4);
      s += __shfl_xor(s, 8);
      rsum[j] = 1.f / s;
    }
    ushort_t* obase = o + (size_t)(brow + q0 + g * 4) * 384 + hh * 64 + r;
#pragma unroll
    for (int j = 0; j < 4; ++j)
#pragma unroll
      for (int dt = 0; dt < 4; ++dt)
        obase[(size_t)j * 384 + dt * 16] = f2b(O[dt][j] * rsum[j]);
  }
}

// -------- loss: grid-stride rows, block-reduce, one atomic per block --------
__global__ __launch_bounds__(256)
void loss_kernel(const float* __restrict__ logits, const int* __restrict__ targets,
                 float* __restrict__ loss_acc, int R) {
  __shared__ float red[4];
  int wid = threadIdx.x >> 6, lane = threadIdx.x & 63;
  float lsum = 0.f;
  for (int r = blockIdx.x * 4 + wid; r < R; r += gridDim.x * 4) {
    const float* lrow = logits + (size_t)r * VV;
    float v = lrow[lane];
    float e64 = lrow[64];
    float m = fmaxf(v, e64);
#pragma unroll
    for (int off = 32; off; off >>= 1) m = fmaxf(m, __shfl_xor(m, off));
    float s = expf(v - m);
#pragma unroll
    for (int off = 32; off; off >>= 1) s += __shfl_xor(s, off);
    s += expf(e64 - m);
    float lse = m + logf(s);
    int t = targets[r];
    float tv = (t < 64) ? __shfl(v, t) : e64;
    lsum += lse - tv;
  }
  if (lane == 0) red[wid] = lsum;
  __syncthreads();
  if (threadIdx.x == 0)
    atomicAdd(loss_acc, (red[0] + red[1] + red[2] + red[3]) * (1.f / BT));
}

// ---------------- launcher ----------------
extern "C" void kernel_launch(void* const* d_in, const int* in_sizes, int n_in,
                              void* d_out, int out_size, void* d_ws, size_t ws_size,
                              hipStream_t stream) {
  const int* inputs = (const int*)d_in[0];
  const int* targets = (const int*)d_in[1];
  const float* tok_emb = (const float*)d_in[2];
  const float* pos_emb = (const float*)d_in[3];
  const float* Wq = (const float*)d_in[4];
  const float* Wk = (const float*)d_in[5];
  const float* Wv = (const float*)d_in[6];
  const float* Wo = (const float*)d_in[7];
  const float* bo = (const float*)d_in[8];
  const float* ln1_g = (const float*)d_in[9];
  const float* ln1_b = (const float*)d_in[10];
  const float* W1 = (const float*)d_in[11];
  const float* b1 = (const float*)d_in[12];
  const float* W2 = (const float*)d_in[13];
  const float* b2 = (const float*)d_in[14];
  const float* ln2_g = (const float*)d_in[15];
  const float* ln2_b = (const float*)d_in[16];
  const float* lnf_g = (const float*)d_in[17];
  const float* lnf_b = (const float*)d_in[18];
  const float* Wh = (const float*)d_in[19];
  const float* bh = (const float*)d_in[20];

  float* logits = (float*)d_out;
  float* loss = logits + (size_t)BT * VV;

  auto al = [](size_t b) { return (b + 255) & ~(size_t)255; };
  const size_t wq_b = al((size_t)LL * 1152 * 384 * 2);
  const size_t wo_b = al((size_t)LL * 384 * 384 * 2);
  const size_t w1_b = al((size_t)LL * 1536 * 384 * 2);
  const size_t wh_b = al((size_t)128 * 384 * 2);
  const size_t wfix = wq_b + wo_b + 2 * w1_b + wh_b;

  int c = BB;                                  // c=256: round-7 A/B showed chunking loses
  while (c > 1 && wfix + (size_t)c * 256 * 6144 > ws_size) c >>= 1;
  const int R = c * TT;
  const int nch = BB / c;

  char* p = (char*)d_ws;
  ushort_t* wqkv = (ushort_t*)p; p += wq_b;
  ushort_t* wot  = (ushort_t*)p; p += wo_b;
  ushort_t* w1t  = (ushort_t*)p; p += w1_b;
  ushort_t* w2t  = (ushort_t*)p; p += w1_b;
  ushort_t* whb  = (ushort_t*)p; p += wh_b;
  ushort_t* x = (ushort_t*)p;    p += (size_t)R * 768;    // [R,384] bf16 residual
  ushort_t* hb = (ushort_t*)p;   p += (size_t)R * 768;    // [R,384] bf16
  ushort_t* ob = (ushort_t*)p;   p += (size_t)R * 768;    // [R,384] bf16
  ushort_t* un = (ushort_t*)p;                            // R*3072 B union
  ushort_t* qkb = un;                                     // [R,768] bf16
  ushort_t* vtb = un + (size_t)R * 768;                   // [384,R] bf16
  ushort_t* midb = un;                                    // [R,1536] bf16

  hipMemsetAsync(loss, 0, 4, stream);
  pack_qkv<<<LL * 1152 * 384 / 256, 256, 0, stream>>>(Wq, Wk, Wv, wqkv);
  pack_wt<<<LL * 384 * 384 / 256, 256, 0, stream>>>(Wo, wot, 384, 384);
  pack_wt<<<LL * 384 * 1536 / 256, 256, 0, stream>>>(W1, w1t, 384, 1536);
  pack_wt<<<LL * 1536 * 384 / 256, 256, 0, stream>>>(W2, w2t, 1536, 384);
  pack_head<<<128 * 384 / 256, 256, 0, stream>>>(Wh, whb);

  const int my = R / 128;
  for (int ch = 0; ch < nch; ++ch) {
    const size_t r0 = (size_t)ch * R;
    embed_ln<<<R / 4, 256, 0, stream>>>(inputs + r0, tok_emb, pos_emb,
                                        ln1_g, ln1_b, x, hb);
    for (int l = 0; l < LL; ++l) {
      gemm_bf16<3, false, false><<<9 * my, 256, 0, stream>>>(
          hb, wqkv + (size_t)l * 1152 * 384, nullptr, qkb, nullptr, vtb, R, 1152, 384, 9);
      attn_kernel<<<c * HH, 512, 0, stream>>>(qkb, vtb, ob, R);
      gemm_resln<<<my, 512, 0, stream>>>(                         // Wo + res + LN(ln2)
          ob, wot + (size_t)l * 384 * 384, bo + l * EE, x,
          ln2_g + l * EE, ln2_b + l * EE, hb, R, 384);
      gemm_bf16<0, true, true><<<12 * my, 256, 0, stream>>>(
          hb, w1t + (size_t)l * 1536 * 384, b1 + l * FF, midb, nullptr, nullptr, R, 1536, 384, 12);
      const float* ng = (l + 1 < LL) ? ln1_g + (l + 1) * EE : lnf_g;
      const float* nb = (l + 1 < LL) ? ln1_b + (l + 1) * EE : lnf_b;
      gemm_resln<<<my, 512, 0, stream>>>(                         // FFN2 + res + LN(next)
          midb, w2t + (size_t)l * 384 * 1536, b2 + l * EE, x, ng, nb, hb, R, 1536);
    }
    gemm_bf16<2, true, false><<<1 * my, 256, 0, stream>>>(
        hb, whb, bh, nullptr, logits + r0 * VV, nullptr, R, 128, 384, 1);
    loss_kernel<<<1024, 256, 0, stream>>>(logits + r0 * VV, targets + r0, loss, R);
  }
}